// Round 2
// baseline (564.061 us; speedup 1.0000x reference)
//
#include <hip/hip_runtime.h>
#include <hip/hip_bf16.h>

#define DEV static __device__ __forceinline__

DEV float silu(float x){ return x / (1.f + __expf(-x)); }

// ---- problem sizes ----
#define BB 4
#define LL 4096          // H*W, H=W=64
#define DM 96
#define DI 192
#define NS 16
#define KK 4
#define RR 6
#define C38 38
#define NC 16            // chunks
#define CL 256           // chunk length

// ---- workspace layout (float offsets); total = 39,059,456 floats = 156.2 MB ----
#define OFF_XIN   0
#define OFF_Z     (OFF_XIN + BB*LL*DI)
#define OFF_XC    (OFF_Z + BB*LL*DI)
#define OFF_DELTA (OFF_XC + BB*LL*DI)
#define OFF_BC    (OFF_DELTA + BB*KK*LL*DI)
#define OFF_YS    (OFF_BC + BB*KK*LL*32)
#define OFF_HLOC  (OFF_YS + BB*KK*LL*DI)
#define OFF_PLOC  (OFF_HLOC + BB*KK*NC*DI*NS)
#define OFF_HINIT (OFF_PLOC + BB*KK*NC*DI*NS)

// spatial position of sequence index t for scan direction k  (H=W=64)
DEV int pos_of(int k, int t){
    int pr = ((t & 63) << 6) | (t >> 6);
    int p  = (k & 1) ? pr : t;
    if (k & 2) p = LL - 1 - p;
    return p;
}

// ---- 1. in_proj: x(16384,96) @ W^T(384,96) -> xin(.,192), z(.,192) ----
__global__ __launch_bounds__(384) void k_inproj(const float* __restrict__ x, const float* __restrict__ w,
                                                float* __restrict__ xin, float* __restrict__ z){
    __shared__ float xs[8][96];
    int tid = threadIdx.x;
    int r0 = blockIdx.x * 8;
    const float* xrow = x + (long)r0 * DM;
    for (int i = tid; i < 8*96; i += 384) xs[i/96][i%96] = xrow[i];
    __syncthreads();
    int j = tid;                         // 0..383 output column
    const float* wr = w + (long)j * DM;
    float acc[8];
#pragma unroll
    for (int r = 0; r < 8; ++r) acc[r] = 0.f;
    for (int kk = 0; kk < DM; ++kk){
        float wv = wr[kk];
#pragma unroll
        for (int r = 0; r < 8; ++r) acc[r] += wv * xs[r][kk];
    }
    if (j < DI){
#pragma unroll
        for (int r = 0; r < 8; ++r) xin[(long)(r0 + r)*DI + j] = acc[r];
    } else {
        int jj = j - DI;
#pragma unroll
        for (int r = 0; r < 8; ++r) z[(long)(r0 + r)*DI + jj] = acc[r];
    }
}

// ---- 2. depthwise 3x3 conv (pad 1) + bias + SiLU, channels-last ----
__global__ __launch_bounds__(256) void k_conv(const float* __restrict__ xin, const float* __restrict__ cw,
                                              const float* __restrict__ cb, float* __restrict__ xc){
    int g = blockIdx.x * 256 + threadIdx.x;   // < BB*LL*DI
    int d = g % DI;
    int l = (g / DI) % LL;
    int b = g / (DI * LL);
    int h = l >> 6, ww = l & 63;
    float acc = cb[d];
    const float* base = xin + (long)b * LL * DI + d;
#pragma unroll
    for (int dy = 0; dy < 3; ++dy){
        int hh = h + dy - 1;
        if (hh < 0 || hh >= 64) continue;
#pragma unroll
        for (int dx = 0; dx < 3; ++dx){
            int wx = ww + dx - 1;
            if (wx < 0 || wx >= 64) continue;
            acc += base[(long)(hh*64 + wx)*DI] * cw[d*9 + dy*3 + dx];
        }
    }
    xc[g] = silu(acc);
}

// ---- 3. x_proj (38 outs) + dt_proj (rank 6) + softplus; emits delta(b,k,t,d), bc(b,k,t,32) ----
__global__ __launch_bounds__(256) void k_xdbl(const float* __restrict__ xc, const float* __restrict__ xpw,
                                              const float* __restrict__ dtw, const float* __restrict__ dtb,
                                              float* __restrict__ delta, float* __restrict__ bc2){
    __shared__ float xs[16][200];   // padded vs bank conflicts
    __shared__ float cc[16][40];
    int tid = threadIdx.x;
    int bk  = blockIdx.x >> 8;       // 16 (b,k) pairs
    int tt  = blockIdx.x & 255;
    int b = bk >> 2, k = bk & 3;
    int t0 = tt * 16;
    for (int i = tid; i < 16*DI; i += 256){
        int r = i / DI, d = i % DI;
        int p = pos_of(k, t0 + r);
        xs[r][d] = xc[((long)b*LL + p)*DI + d];
    }
    __syncthreads();
    int t = tid >> 4, cs = tid & 15;
    const float* wbase = xpw + (long)k * C38 * DI;
#pragma unroll
    for (int jj = 0; jj < 3; ++jj){
        int c = cs + 16*jj;
        if (c < C38){
            const float* wr = wbase + (long)c * DI;
            float acc = 0.f;
            for (int d = 0; d < DI; ++d) acc += xs[t][d] * wr[d];
            cc[t][c] = acc;
        }
    }
    __syncthreads();
    long obase = (long)bk * LL + t0;
    for (int i = tid; i < 16*DI; i += 256){
        int r = i / DI, d = i % DI;
        float raw = dtb[k*DI + d];
        const float* dw = dtw + ((long)k*DI + d) * RR;
#pragma unroll
        for (int rr = 0; rr < RR; ++rr) raw += cc[r][rr] * dw[rr];
        float sp = (raw > 15.f) ? raw : __logf(1.f + __expf(raw));
        delta[(obase + r)*DI + d] = sp;
    }
    for (int i = tid; i < 16*32; i += 256){
        int r = i >> 5, q = i & 31;
        bc2[(obase + r)*32 + q] = cc[r][6 + q];   // q<16 -> B_n, q>=16 -> C_n
    }
}

// ---- 4. scan pass A: per-chunk local end-state + decay product. thread = (d, n-pair) ----
__global__ __launch_bounds__(256) void k_scanA(const float* __restrict__ delta, const float* __restrict__ bc2,
                                               const float* __restrict__ xc, const float* __restrict__ alog,
                                               float* __restrict__ hloc, float* __restrict__ ploc){
    int tid = threadIdx.x;
    int j = tid & 7, dl = tid >> 3;                 // j: n-pair index, dl: 0..31
    int bid = blockIdx.x;
    int dg = bid % 6; int c = (bid/6) & 15; int k = (bid/96) & 3; int b = bid/384;
    int d = dg*32 + dl;
    int n0 = j*2;
    float a0 = -__expf(alog[(k*DI + d)*NS + n0]);
    float a1 = -__expf(alog[(k*DI + d)*NS + n0 + 1]);
    int bk = b*4 + k;
    int t0 = c * CL;
    const float* dep = delta + ((long)bk*LL + t0)*DI + d;
    const float* bcp = bc2   + ((long)bk*LL + t0)*32 + n0;
    const float* xcb = xc    + (long)b*LL*DI + d;
    float h0=0.f, h1=0.f, p0=1.f, p1=1.f;
#pragma unroll 4
    for (int i = 0; i < CL; ++i){
        int p = pos_of(k, t0 + i);
        float de = *dep;
        float u  = xcb[(long)p*DI];
        float2 bv = *(const float2*)bcp;
        float dA0 = __expf(de*a0), dA1 = __expf(de*a1);
        float du = de * u;
        h0 = h0*dA0 + du*bv.x;
        h1 = h1*dA1 + du*bv.y;
        p0 *= dA0; p1 *= dA1;
        dep += DI; bcp += 32;
    }
    long off = (((long)bk*NC + c)*DI + d)*NS + n0;
    *(float2*)(hloc + off) = make_float2(h0, h1);
    *(float2*)(ploc + off) = make_float2(p0, p1);
}

// ---- 5. scan pass B: sequential chunk combine (tiny) ----
__global__ __launch_bounds__(256) void k_scanB(const float* __restrict__ hloc, const float* __restrict__ ploc,
                                               float* __restrict__ hinit){
    int gid = blockIdx.x * 256 + threadIdx.x;       // < BB*KK*DI*NS = 49152
    int dn = gid % (DI*NS);
    int bk = gid / (DI*NS);
    long base = (long)bk * NC * DI * NS + dn;
    float h = 0.f;
#pragma unroll
    for (int c = 0; c < NC; ++c){
        long o = base + (long)c * DI * NS;
        hinit[o] = h;
        h = h * ploc[o] + hloc[o];
    }
}

// ---- 6. scan pass C: replay with correct initial state, emit y at SPATIAL position ----
__global__ __launch_bounds__(256) void k_scanC(const float* __restrict__ delta, const float* __restrict__ bc2,
                                               const float* __restrict__ xc, const float* __restrict__ alog,
                                               const float* __restrict__ hinit, float* __restrict__ ys){
    int tid = threadIdx.x;
    int j = tid & 7, dl = tid >> 3;
    int bid = blockIdx.x;
    int dg = bid % 6; int c = (bid/6) & 15; int k = (bid/96) & 3; int b = bid/384;
    int d = dg*32 + dl;
    int n0 = j*2;
    float a0 = -__expf(alog[(k*DI + d)*NS + n0]);
    float a1 = -__expf(alog[(k*DI + d)*NS + n0 + 1]);
    int bk = b*4 + k;
    int t0 = c * CL;
    const float* dep = delta + ((long)bk*LL + t0)*DI + d;
    const float* bcp = bc2   + ((long)bk*LL + t0)*32 + n0;
    const float* xcb = xc    + (long)b*LL*DI + d;
    long off = (((long)bk*NC + c)*DI + d)*NS + n0;
    float2 hi = *(const float2*)(hinit + off);
    float h0 = hi.x, h1 = hi.y;
    float* ysb = ys + (long)bk*LL*DI + d;
#pragma unroll 4
    for (int i = 0; i < CL; ++i){
        int p = pos_of(k, t0 + i);
        float de = *dep;
        float u  = xcb[(long)p*DI];
        float2 bv = *(const float2*)bcp;
        float2 cv = *(const float2*)(bcp + 16);
        float dA0 = __expf(de*a0), dA1 = __expf(de*a1);
        float du = de * u;
        h0 = h0*dA0 + du*bv.x;
        h1 = h1*dA1 + du*bv.y;
        float y = h0*cv.x + h1*cv.y;
        y += __shfl_xor(y, 1, 64);
        y += __shfl_xor(y, 2, 64);
        y += __shfl_xor(y, 4, 64);
        if (j == 0) ysb[(long)p*DI] = y;
        dep += DI; bcp += 32;
    }
}

// ---- 7. merge(4 dirs) + D*u skip + LayerNorm + SiLU gate + out_proj -> fp32 out ----
__global__ __launch_bounds__(192) void k_fuse(const float* __restrict__ ys, const float* __restrict__ xc,
                                              const float* __restrict__ z, const float* __restrict__ Dsk,
                                              const float* __restrict__ lnw, const float* __restrict__ lnb,
                                              const float* __restrict__ wout, float* __restrict__ out){
    __shared__ float yv[4][DI];
    __shared__ float red[2][3];
    __shared__ float part[2][4][96];
    int tid = threadIdx.x;                 // 0..191, = d
    int b  = blockIdx.x / (LL/4);
    int p0 = (blockIdx.x % (LL/4)) * 4;
    int d = tid;
    float sumD = Dsk[d] + Dsk[DI + d] + Dsk[2*DI + d] + Dsk[3*DI + d];
    float lw = lnw[d], lb = lnb[d];
    for (int pp = 0; pp < 4; ++pp){
        int p = p0 + pp;
        long yb = ((long)b*4)*LL*DI + (long)p*DI + d;
        float y = ys[yb] + ys[yb + (long)LL*DI] + ys[yb + 2L*LL*DI] + ys[yb + 3L*LL*DI];
        y += xc[((long)b*LL + p)*DI + d] * sumD;
        float s = y, sq = y*y;
#pragma unroll
        for (int m = 32; m > 0; m >>= 1){ s += __shfl_down(s, m, 64); sq += __shfl_down(sq, m, 64); }
        int wvi = tid >> 6, ln = tid & 63;
        if (ln == 0){ red[0][wvi] = s; red[1][wvi] = sq; }
        __syncthreads();
        float st  = red[0][0] + red[0][1] + red[0][2];
        float sqt = red[1][0] + red[1][1] + red[1][2];
        float mu  = st / DI;
        float var = sqt / DI - mu*mu;
        float rs  = rsqrtf(var + 1e-5f);
        float yn  = (y - mu)*rs*lw + lb;
        float zg  = z[((long)b*LL + p)*DI + d];
        yv[pp][d] = yn * silu(zg);
        __syncthreads();
    }
    // out_proj: 96 outputs, split K=192 over two halves of the block
    int m = tid % 96, half = tid / 96;
    float acc[4] = {0.f, 0.f, 0.f, 0.f};
    const float* wr = wout + (long)m*DI + half*96;
    for (int dd = 0; dd < 96; ++dd){
        float wv = wr[dd];
        int df = half*96 + dd;
#pragma unroll
        for (int pp = 0; pp < 4; ++pp) acc[pp] += wv * yv[pp][df];
    }
#pragma unroll
    for (int pp = 0; pp < 4; ++pp) part[half][pp][m] = acc[pp];
    __syncthreads();
    if (tid < 96){
#pragma unroll
        for (int pp = 0; pp < 4; ++pp){
            float v = part[0][pp][tid] + part[1][pp][tid];
            out[((long)b*LL + p0 + pp)*DM + tid] = v;
        }
    }
}

extern "C" void kernel_launch(void* const* d_in, const int* in_sizes, int n_in,
                              void* d_out, int out_size, void* d_ws, size_t ws_size,
                              hipStream_t stream){
    (void)in_sizes; (void)n_in; (void)out_size; (void)ws_size;
    const float* x    = (const float*)d_in[0];
    const float* win  = (const float*)d_in[1];
    const float* cw   = (const float*)d_in[2];
    const float* cb   = (const float*)d_in[3];
    const float* xpw  = (const float*)d_in[4];
    const float* dtw  = (const float*)d_in[5];
    const float* dtb  = (const float*)d_in[6];
    const float* alog = (const float*)d_in[7];
    const float* ds   = (const float*)d_in[8];
    const float* lnw  = (const float*)d_in[9];
    const float* lnb  = (const float*)d_in[10];
    const float* wout = (const float*)d_in[11];

    float* ws    = (float*)d_ws;
    float* xin   = ws + OFF_XIN;
    float* z     = ws + OFF_Z;
    float* xc    = ws + OFF_XC;
    float* delta = ws + OFF_DELTA;
    float* bc2   = ws + OFF_BC;
    float* ysb   = ws + OFF_YS;
    float* hloc  = ws + OFF_HLOC;
    float* ploc  = ws + OFF_PLOC;
    float* hinit = ws + OFF_HINIT;

    k_inproj<<<dim3(2048), dim3(384), 0, stream>>>(x, win, xin, z);
    k_conv  <<<dim3(12288), dim3(256), 0, stream>>>(xin, cw, cb, xc);
    k_xdbl  <<<dim3(4096), dim3(256), 0, stream>>>(xc, xpw, dtw, dtb, delta, bc2);
    k_scanA <<<dim3(1536), dim3(256), 0, stream>>>(delta, bc2, xc, alog, hloc, ploc);
    k_scanB <<<dim3(192),  dim3(256), 0, stream>>>(hloc, ploc, hinit);
    k_scanC <<<dim3(1536), dim3(256), 0, stream>>>(delta, bc2, xc, alog, hinit, ysb);
    k_fuse  <<<dim3(4096), dim3(192), 0, stream>>>(ysb, xc, z, ds, lnw, lnb, wout,
                                                   (float*)d_out);
}

// Round 3
// 399.508 us; speedup vs baseline: 1.4119x; 1.4119x over previous
//
#include <hip/hip_runtime.h>
#include <hip/hip_bf16.h>

#define DEV static __device__ __forceinline__

DEV float silu(float x){ return x / (1.f + __expf(-x)); }

// ---- problem sizes ----
#define BB 4
#define LL 4096          // H*W, H=W=64
#define DM 96
#define DI 192
#define NS 16
#define KK 4
#define RR 6
#define C38 38
#define NC 16            // chunks
#define CL 256           // chunk length

// ---- workspace layout (float offsets) ----
#define OFF_XIN   0
#define OFF_Z     (OFF_XIN + BB*LL*DI)
#define OFF_XC    (OFF_Z + BB*LL*DI)
#define OFF_DELTA (OFF_XC + BB*LL*DI)
#define OFF_BC    (OFF_DELTA + BB*KK*LL*DI)
#define OFF_YS    (OFF_BC + BB*KK*LL*32)
#define OFF_HLOC  (OFF_YS + BB*KK*LL*DI)
#define OFF_PLOC  (OFF_HLOC + BB*KK*NC*DI*NS)
#define OFF_HINIT (OFF_PLOC + BB*KK*NC*DI*NS)

// spatial position of sequence index t for scan direction k  (H=W=64)
DEV int pos_of(int k, int t){
    int pr = ((t & 63) << 6) | (t >> 6);
    int p  = (k & 1) ? pr : t;
    if (k & 2) p = LL - 1 - p;
    return p;
}

// ---- 1. in_proj: x(16384,96) @ W^T(384,96) -> xin(.,192), z(.,192) ----
__global__ __launch_bounds__(384) void k_inproj(const float* __restrict__ x, const float* __restrict__ w,
                                                float* __restrict__ xin, float* __restrict__ z){
    __shared__ float xs[8][96];
    int tid = threadIdx.x;
    int r0 = blockIdx.x * 8;
    const float* xrow = x + (long)r0 * DM;
    for (int i = tid; i < 8*96; i += 384) xs[i/96][i%96] = xrow[i];
    __syncthreads();
    int j = tid;                         // 0..383 output column
    const float* wr = w + (long)j * DM;
    float acc[8];
#pragma unroll
    for (int r = 0; r < 8; ++r) acc[r] = 0.f;
    for (int kk = 0; kk < DM; ++kk){
        float wv = wr[kk];
#pragma unroll
        for (int r = 0; r < 8; ++r) acc[r] += wv * xs[r][kk];
    }
    if (j < DI){
#pragma unroll
        for (int r = 0; r < 8; ++r) xin[(long)(r0 + r)*DI + j] = acc[r];
    } else {
        int jj = j - DI;
#pragma unroll
        for (int r = 0; r < 8; ++r) z[(long)(r0 + r)*DI + jj] = acc[r];
    }
}

// ---- 2. depthwise 3x3 conv (pad 1) + bias + SiLU, channels-last ----
__global__ __launch_bounds__(256) void k_conv(const float* __restrict__ xin, const float* __restrict__ cw,
                                              const float* __restrict__ cb, float* __restrict__ xc){
    int g = blockIdx.x * 256 + threadIdx.x;   // < BB*LL*DI
    int d = g % DI;
    int l = (g / DI) % LL;
    int b = g / (DI * LL);
    int h = l >> 6, ww = l & 63;
    float acc = cb[d];
    const float* base = xin + (long)b * LL * DI + d;
#pragma unroll
    for (int dy = 0; dy < 3; ++dy){
        int hh = h + dy - 1;
        if (hh < 0 || hh >= 64) continue;
#pragma unroll
        for (int dx = 0; dx < 3; ++dx){
            int wx = ww + dx - 1;
            if (wx < 0 || wx >= 64) continue;
            acc += base[(long)(hh*64 + wx)*DI] * cw[d*9 + dy*3 + dx];
        }
    }
    xc[g] = silu(acc);
}

// ---- 3. x_proj (38 outs) + dt_proj (rank 6) + softplus — LDS-tiled GEMM ----
// block = one (b,k) x 32 time steps; 256 threads
__global__ __launch_bounds__(256) void k_xdbl(const float* __restrict__ xc, const float* __restrict__ xpw,
                                              const float* __restrict__ dtw, const float* __restrict__ dtb,
                                              float* __restrict__ delta, float* __restrict__ bc2){
    __shared__ float xsT[192][33];    // x tile, transposed: [d][t], pad 33 -> conflict-free column reads
    __shared__ float wsm[40*192];     // W[k] rows (38 used, 2 pad rows may hold garbage)
    __shared__ float ccs[32][41];     // projection outputs per t (38 used)
    __shared__ float dtws[192*6];     // dt_proj weight slice
    int tid = threadIdx.x;
    int bk   = blockIdx.x >> 7;       // 2048 blocks: 16 (b,k) x 128 tiles
    int tile = blockIdx.x & 127;
    int b = bk >> 2, k = bk & 3;
    int t0 = tile * 32;

    const float* wg = xpw + (long)k * C38 * DI;
    for (int i = tid; i < C38*DI; i += 256) wsm[i] = wg[i];
    const float* dg = dtw + (long)k * DI * RR;
    for (int i = tid; i < DI*RR; i += 256) dtws[i] = dg[i];
    for (int i = tid; i < 32*DI; i += 256){
        int r = i / DI, d = i - r*DI;
        int p = pos_of(k, t0 + r);
        xsT[d][r] = xc[((long)b*LL + p)*DI + d];
    }
    __syncthreads();

    int t = tid & 31, cg = tid >> 5;          // cg in 0..7; c = cg + 8*jj
    float acc[5] = {0.f, 0.f, 0.f, 0.f, 0.f};
    for (int d = 0; d < DI; d += 4){
        float x0 = xsT[d+0][t], x1 = xsT[d+1][t], x2 = xsT[d+2][t], x3 = xsT[d+3][t];
#pragma unroll
        for (int jj = 0; jj < 5; ++jj){
            int c = cg + 8*jj;                // c<38 valid; 38..39 read pad rows (discarded)
            const float4 wv = *(const float4*)&wsm[c*DI + d];
            acc[jj] += x0*wv.x + x1*wv.y + x2*wv.z + x3*wv.w;
        }
    }
#pragma unroll
    for (int jj = 0; jj < 5; ++jj){
        int c = cg + 8*jj;
        if (c < C38) ccs[t][c] = acc[jj];
    }
    __syncthreads();

    long obase = (long)bk * LL + t0;
    for (int i = tid; i < 32*DI; i += 256){
        int r = i / DI, d = i - r*DI;
        float raw = dtb[k*DI + d];
#pragma unroll
        for (int rr = 0; rr < RR; ++rr) raw += ccs[r][rr] * dtws[d*RR + rr];
        float sp = (raw > 15.f) ? raw : __logf(1.f + __expf(raw));
        delta[(obase + r)*DI + d] = sp;
    }
    for (int i = tid; i < 32*32; i += 256){
        int r = i >> 5, q = i & 31;
        bc2[(obase + r)*32 + q] = ccs[r][6 + q];   // q<16 -> B_n, q>=16 -> C_n
    }
}

// ---- 4. scan pass A: per-chunk local end-state + decay product. thread = (d, n-pair) ----
__global__ __launch_bounds__(256) void k_scanA(const float* __restrict__ delta, const float* __restrict__ bc2,
                                               const float* __restrict__ xc, const float* __restrict__ alog,
                                               float* __restrict__ hloc, float* __restrict__ ploc){
    int tid = threadIdx.x;
    int j = tid & 7, dl = tid >> 3;                 // j: n-pair index, dl: 0..31
    int bid = blockIdx.x;
    int dg = bid % 6; int c = (bid/6) & 15; int k = (bid/96) & 3; int b = bid/384;
    int d = dg*32 + dl;
    int n0 = j*2;
    float a0 = -__expf(alog[(k*DI + d)*NS + n0]);
    float a1 = -__expf(alog[(k*DI + d)*NS + n0 + 1]);
    int bk = b*4 + k;
    int t0 = c * CL;
    const float* dep = delta + ((long)bk*LL + t0)*DI + d;
    const float* bcp = bc2   + ((long)bk*LL + t0)*32 + n0;
    const float* xcb = xc    + (long)b*LL*DI + d;
    float h0=0.f, h1=0.f, p0=1.f, p1=1.f;
#pragma unroll 4
    for (int i = 0; i < CL; ++i){
        int p = pos_of(k, t0 + i);
        float de = *dep;
        float u  = xcb[(long)p*DI];
        float2 bv = *(const float2*)bcp;
        float dA0 = __expf(de*a0), dA1 = __expf(de*a1);
        float du = de * u;
        h0 = h0*dA0 + du*bv.x;
        h1 = h1*dA1 + du*bv.y;
        p0 *= dA0; p1 *= dA1;
        dep += DI; bcp += 32;
    }
    long off = (((long)bk*NC + c)*DI + d)*NS + n0;
    *(float2*)(hloc + off) = make_float2(h0, h1);
    *(float2*)(ploc + off) = make_float2(p0, p1);
}

// ---- 5. scan pass B: sequential chunk combine (tiny) ----
__global__ __launch_bounds__(256) void k_scanB(const float* __restrict__ hloc, const float* __restrict__ ploc,
                                               float* __restrict__ hinit){
    int gid = blockIdx.x * 256 + threadIdx.x;       // < BB*KK*DI*NS = 49152
    int dn = gid % (DI*NS);
    int bk = gid / (DI*NS);
    long base = (long)bk * NC * DI * NS + dn;
    float h = 0.f;
#pragma unroll
    for (int c = 0; c < NC; ++c){
        long o = base + (long)c * DI * NS;
        hinit[o] = h;
        h = h * ploc[o] + hloc[o];
    }
}

// ---- 6. scan pass C: replay with correct initial state, emit y at SPATIAL position ----
__global__ __launch_bounds__(256) void k_scanC(const float* __restrict__ delta, const float* __restrict__ bc2,
                                               const float* __restrict__ xc, const float* __restrict__ alog,
                                               const float* __restrict__ hinit, float* __restrict__ ys){
    int tid = threadIdx.x;
    int j = tid & 7, dl = tid >> 3;
    int bid = blockIdx.x;
    int dg = bid % 6; int c = (bid/6) & 15; int k = (bid/96) & 3; int b = bid/384;
    int d = dg*32 + dl;
    int n0 = j*2;
    float a0 = -__expf(alog[(k*DI + d)*NS + n0]);
    float a1 = -__expf(alog[(k*DI + d)*NS + n0 + 1]);
    int bk = b*4 + k;
    int t0 = c * CL;
    const float* dep = delta + ((long)bk*LL + t0)*DI + d;
    const float* bcp = bc2   + ((long)bk*LL + t0)*32 + n0;
    const float* xcb = xc    + (long)b*LL*DI + d;
    long off = (((long)bk*NC + c)*DI + d)*NS + n0;
    float2 hi = *(const float2*)(hinit + off);
    float h0 = hi.x, h1 = hi.y;
    float* ysb = ys + (long)bk*LL*DI + d;
#pragma unroll 4
    for (int i = 0; i < CL; ++i){
        int p = pos_of(k, t0 + i);
        float de = *dep;
        float u  = xcb[(long)p*DI];
        float2 bv = *(const float2*)bcp;
        float2 cv = *(const float2*)(bcp + 16);
        float dA0 = __expf(de*a0), dA1 = __expf(de*a1);
        float du = de * u;
        h0 = h0*dA0 + du*bv.x;
        h1 = h1*dA1 + du*bv.y;
        float y = h0*cv.x + h1*cv.y;
        y += __shfl_xor(y, 1, 64);
        y += __shfl_xor(y, 2, 64);
        y += __shfl_xor(y, 4, 64);
        if (j == 0) ysb[(long)p*DI] = y;
        dep += DI; bcp += 32;
    }
}

// ---- 7. merge(4 dirs) + D*u skip + LayerNorm + SiLU gate + out_proj -> fp32 out ----
__global__ __launch_bounds__(192) void k_fuse(const float* __restrict__ ys, const float* __restrict__ xc,
                                              const float* __restrict__ z, const float* __restrict__ Dsk,
                                              const float* __restrict__ lnw, const float* __restrict__ lnb,
                                              const float* __restrict__ wout, float* __restrict__ out){
    __shared__ float yv[4][DI];
    __shared__ float red[2][3];
    __shared__ float part[2][4][96];
    int tid = threadIdx.x;                 // 0..191, = d
    int b  = blockIdx.x / (LL/4);
    int p0 = (blockIdx.x % (LL/4)) * 4;
    int d = tid;
    float sumD = Dsk[d] + Dsk[DI + d] + Dsk[2*DI + d] + Dsk[3*DI + d];
    float lw = lnw[d], lb = lnb[d];
    for (int pp = 0; pp < 4; ++pp){
        int p = p0 + pp;
        long yb = ((long)b*4)*LL*DI + (long)p*DI + d;
        float y = ys[yb] + ys[yb + (long)LL*DI] + ys[yb + 2L*LL*DI] + ys[yb + 3L*LL*DI];
        y += xc[((long)b*LL + p)*DI + d] * sumD;
        float s = y, sq = y*y;
#pragma unroll
        for (int m = 32; m > 0; m >>= 1){ s += __shfl_down(s, m, 64); sq += __shfl_down(sq, m, 64); }
        int wvi = tid >> 6, ln = tid & 63;
        if (ln == 0){ red[0][wvi] = s; red[1][wvi] = sq; }
        __syncthreads();
        float st  = red[0][0] + red[0][1] + red[0][2];
        float sqt = red[1][0] + red[1][1] + red[1][2];
        float mu  = st / DI;
        float var = sqt / DI - mu*mu;
        float rs  = rsqrtf(var + 1e-5f);
        float yn  = (y - mu)*rs*lw + lb;
        float zg  = z[((long)b*LL + p)*DI + d];
        yv[pp][d] = yn * silu(zg);
        __syncthreads();
    }
    // out_proj: 96 outputs, split K=192 over two halves of the block
    int m = tid % 96, half = tid / 96;
    float acc[4] = {0.f, 0.f, 0.f, 0.f};
    const float* wr = wout + (long)m*DI + half*96;
    for (int dd = 0; dd < 96; ++dd){
        float wv = wr[dd];
        int df = half*96 + dd;
#pragma unroll
        for (int pp = 0; pp < 4; ++pp) acc[pp] += wv * yv[pp][df];
    }
#pragma unroll
    for (int pp = 0; pp < 4; ++pp) part[half][pp][m] = acc[pp];
    __syncthreads();
    if (tid < 96){
#pragma unroll
        for (int pp = 0; pp < 4; ++pp){
            float v = part[0][pp][tid] + part[1][pp][tid];
            out[((long)b*LL + p0 + pp)*DM + tid] = v;
        }
    }
}

extern "C" void kernel_launch(void* const* d_in, const int* in_sizes, int n_in,
                              void* d_out, int out_size, void* d_ws, size_t ws_size,
                              hipStream_t stream){
    (void)in_sizes; (void)n_in; (void)out_size; (void)ws_size;
    const float* x    = (const float*)d_in[0];
    const float* win  = (const float*)d_in[1];
    const float* cw   = (const float*)d_in[2];
    const float* cb   = (const float*)d_in[3];
    const float* xpw  = (const float*)d_in[4];
    const float* dtw  = (const float*)d_in[5];
    const float* dtb  = (const float*)d_in[6];
    const float* alog = (const float*)d_in[7];
    const float* ds   = (const float*)d_in[8];
    const float* lnw  = (const float*)d_in[9];
    const float* lnb  = (const float*)d_in[10];
    const float* wout = (const float*)d_in[11];

    float* ws    = (float*)d_ws;
    float* xin   = ws + OFF_XIN;
    float* z     = ws + OFF_Z;
    float* xc    = ws + OFF_XC;
    float* delta = ws + OFF_DELTA;
    float* bc2   = ws + OFF_BC;
    float* ysb   = ws + OFF_YS;
    float* hloc  = ws + OFF_HLOC;
    float* ploc  = ws + OFF_PLOC;
    float* hinit = ws + OFF_HINIT;

    k_inproj<<<dim3(2048), dim3(384), 0, stream>>>(x, win, xin, z);
    k_conv  <<<dim3(12288), dim3(256), 0, stream>>>(xin, cw, cb, xc);
    k_xdbl  <<<dim3(2048), dim3(256), 0, stream>>>(xc, xpw, dtw, dtb, delta, bc2);
    k_scanA <<<dim3(1536), dim3(256), 0, stream>>>(delta, bc2, xc, alog, hloc, ploc);
    k_scanB <<<dim3(192),  dim3(256), 0, stream>>>(hloc, ploc, hinit);
    k_scanC <<<dim3(1536), dim3(256), 0, stream>>>(delta, bc2, xc, alog, hinit, ysb);
    k_fuse  <<<dim3(4096), dim3(192), 0, stream>>>(ysb, xc, z, ds, lnw, lnb, wout,
                                                   (float*)d_out);
}

// Round 4
// 304.299 us; speedup vs baseline: 1.8536x; 1.3129x over previous
//
#include <hip/hip_runtime.h>
#include <hip/hip_bf16.h>

#define DEV static __device__ __forceinline__

DEV float silu(float x){ return x / (1.f + __expf(-x)); }

// ---- problem sizes ----
#define BB 4
#define LL 4096          // H*W, H=W=64
#define DM 96
#define DI 192
#define NS 16
#define KK 4
#define RR 6
#define C38 38
#define NC 64            // chunks
#define CL 64            // chunk length (CL=64 makes every scan direction a pure strided walk)

// ---- workspace layout (float offsets); total = 36,896,768 floats = 147.6 MB ----
#define OFF_XIN   0
#define OFF_Z     (OFF_XIN + BB*LL*DI)
#define OFF_XC    (OFF_Z + BB*LL*DI)
#define OFF_DELTA (OFF_XC + BB*LL*DI)
#define OFF_BC    (OFF_DELTA + BB*KK*LL*DI)
#define OFF_YS    (OFF_BC + BB*KK*LL*32)
#define OFF_S     (OFF_YS + BB*KK*LL*DI)
// hloc (BB*KK*NC*DI*NS = 3,145,728 floats) aliases XIN (dead after k_conv)
#define OFF_HLOC  OFF_XIN

// spatial position of sequence index t for scan direction k  (H=W=64)
DEV int pos_of(int k, int t){
    int pr = ((t & 63) << 6) | (t >> 6);
    int p  = (k & 1) ? pr : t;
    if (k & 2) p = LL - 1 - p;
    return p;
}

// ---- 1. in_proj: x(16384,96) @ W^T(384,96) -> xin(.,192), z(.,192) ----
__global__ __launch_bounds__(384) void k_inproj(const float* __restrict__ x, const float* __restrict__ w,
                                                float* __restrict__ xin, float* __restrict__ z){
    __shared__ float xs[8][96];
    int tid = threadIdx.x;
    int r0 = blockIdx.x * 8;
    const float* xrow = x + (long)r0 * DM;
    for (int i = tid; i < 8*96; i += 384) xs[i/96][i%96] = xrow[i];
    __syncthreads();
    int j = tid;                         // 0..383 output column
    const float* wr = w + (long)j * DM;
    float acc[8];
#pragma unroll
    for (int r = 0; r < 8; ++r) acc[r] = 0.f;
    for (int kk = 0; kk < DM; ++kk){
        float wv = wr[kk];
#pragma unroll
        for (int r = 0; r < 8; ++r) acc[r] += wv * xs[r][kk];
    }
    if (j < DI){
#pragma unroll
        for (int r = 0; r < 8; ++r) xin[(long)(r0 + r)*DI + j] = acc[r];
    } else {
        int jj = j - DI;
#pragma unroll
        for (int r = 0; r < 8; ++r) z[(long)(r0 + r)*DI + jj] = acc[r];
    }
}

// ---- 2. depthwise 3x3 conv (pad 1) + bias + SiLU, channels-last ----
__global__ __launch_bounds__(256) void k_conv(const float* __restrict__ xin, const float* __restrict__ cw,
                                              const float* __restrict__ cb, float* __restrict__ xc){
    int g = blockIdx.x * 256 + threadIdx.x;   // < BB*LL*DI
    int d = g % DI;
    int l = (g / DI) % LL;
    int b = g / (DI * LL);
    int h = l >> 6, ww = l & 63;
    float acc = cb[d];
    const float* base = xin + (long)b * LL * DI + d;
#pragma unroll
    for (int dy = 0; dy < 3; ++dy){
        int hh = h + dy - 1;
        if (hh < 0 || hh >= 64) continue;
#pragma unroll
        for (int dx = 0; dx < 3; ++dx){
            int wx = ww + dx - 1;
            if (wx < 0 || wx >= 64) continue;
            acc += base[(long)(hh*64 + wx)*DI] * cw[d*9 + dy*3 + dx];
        }
    }
    xc[g] = silu(acc);
}

// ---- 3. x_proj (38 outs) + dt_proj (rank 6) + softplus — LDS-tiled GEMM ----
__global__ __launch_bounds__(256) void k_xdbl(const float* __restrict__ xc, const float* __restrict__ xpw,
                                              const float* __restrict__ dtw, const float* __restrict__ dtb,
                                              float* __restrict__ delta, float* __restrict__ bc2){
    __shared__ float xsT[192][33];
    __shared__ float wsm[40*192];
    __shared__ float ccs[32][41];
    __shared__ float dtws[192*6];
    int tid = threadIdx.x;
    int bk   = blockIdx.x >> 7;
    int tile = blockIdx.x & 127;
    int b = bk >> 2, k = bk & 3;
    int t0 = tile * 32;

    const float* wg = xpw + (long)k * C38 * DI;
    for (int i = tid; i < C38*DI; i += 256) wsm[i] = wg[i];
    const float* dg = dtw + (long)k * DI * RR;
    for (int i = tid; i < DI*RR; i += 256) dtws[i] = dg[i];
    for (int i = tid; i < 32*DI; i += 256){
        int r = i / DI, d = i - r*DI;
        int p = pos_of(k, t0 + r);
        xsT[d][r] = xc[((long)b*LL + p)*DI + d];
    }
    __syncthreads();

    int t = tid & 31, cg = tid >> 5;
    float acc[5] = {0.f, 0.f, 0.f, 0.f, 0.f};
    for (int d = 0; d < DI; d += 4){
        float x0 = xsT[d+0][t], x1 = xsT[d+1][t], x2 = xsT[d+2][t], x3 = xsT[d+3][t];
#pragma unroll
        for (int jj = 0; jj < 5; ++jj){
            int c = cg + 8*jj;
            const float4 wv = *(const float4*)&wsm[c*DI + d];
            acc[jj] += x0*wv.x + x1*wv.y + x2*wv.z + x3*wv.w;
        }
    }
#pragma unroll
    for (int jj = 0; jj < 5; ++jj){
        int c = cg + 8*jj;
        if (c < C38) ccs[t][c] = acc[jj];
    }
    __syncthreads();

    long obase = (long)bk * LL + t0;
    for (int i = tid; i < 32*DI; i += 256){
        int r = i / DI, d = i - r*DI;
        float raw = dtb[k*DI + d];
#pragma unroll
        for (int rr = 0; rr < RR; ++rr) raw += ccs[r][rr] * dtws[d*RR + rr];
        float sp = (raw > 15.f) ? raw : __logf(1.f + __expf(raw));
        delta[(obase + r)*DI + d] = sp;
    }
    for (int i = tid; i < 32*32; i += 256){
        int r = i >> 5, q = i & 31;
        bc2[(obase + r)*32 + q] = ccs[r][6 + q];
    }
}

// ---- 4. scan pass A: per-chunk local end-state (8 n-states/thread) + delta-sum ----
// block = 192 threads (96 d x 2 j); grid = 16 bk x 64 c x 2 dg = 2048
__global__ __launch_bounds__(192) void k_scanA(const float* __restrict__ delta, const float* __restrict__ bc2,
                                               const float* __restrict__ xc, const float* __restrict__ alog,
                                               float* __restrict__ hloc, float* __restrict__ Ssum){
    int tid = threadIdx.x;
    int j = tid & 1, dl = tid >> 1;
    int bid = blockIdx.x;
    int dg = bid & 1; int c = (bid >> 1) & 63; int bk = bid >> 7;
    int b = bk >> 2, k = bk & 3;
    int d = dg*96 + dl;
    int n0 = j*8;
    float a[8]; bool fast = true;
#pragma unroll
    for (int n = 0; n < 8; ++n){
        a[n] = -__expf(alog[(k*DI + d)*NS + n0 + n]);
        fast = fast && (fabsf(a[n] + (float)(n0 + n + 1)) < 1e-4f*(float)(n0 + n + 1));
    }
    int t0 = c * CL;
    int p0, st;
    if (k == 0){ p0 = t0;         st = 1;   }
    else if (k == 1){ p0 = c;     st = 64;  }
    else if (k == 2){ p0 = LL-1-t0; st = -1;  }
    else            { p0 = LL-1-c;  st = -64; }
    const float* dep = delta + ((long)bk*LL + t0)*DI + d;
    const float* bcp = bc2   + ((long)bk*LL + t0)*32 + n0;
    const float* up  = xc + ((long)b*LL + p0)*DI + d;
    long ustep = (long)st * DI;
    float h[8] = {0,0,0,0,0,0,0,0};
    float S = 0.f;
    if (fast){
        for (int i = 0; i < CL; ++i){
            float de = *dep;
            float u  = *up;
            float4 bv0 = *(const float4*)(bcp);
            float4 bv1 = *(const float4*)(bcp + 4);
            float E  = __expf(-de);
            float E2 = E*E, E4 = E2*E2, E8 = E4*E4;
            float e  = j ? E8 : 1.f;
            float du = de * u;
            S += de;
            float bb[8] = {bv0.x,bv0.y,bv0.z,bv0.w,bv1.x,bv1.y,bv1.z,bv1.w};
#pragma unroll
            for (int n = 0; n < 8; ++n){ e *= E; h[n] = h[n]*e + du*bb[n]; }
            dep += DI; up += ustep; bcp += 32;
        }
    } else {
        for (int i = 0; i < CL; ++i){
            float de = *dep;
            float u  = *up;
            float4 bv0 = *(const float4*)(bcp);
            float4 bv1 = *(const float4*)(bcp + 4);
            float du = de * u;
            S += de;
            float bb[8] = {bv0.x,bv0.y,bv0.z,bv0.w,bv1.x,bv1.y,bv1.z,bv1.w};
#pragma unroll
            for (int n = 0; n < 8; ++n){ float dA = __expf(de*a[n]); h[n] = h[n]*dA + du*bb[n]; }
            dep += DI; up += ustep; bcp += 32;
        }
    }
    long ho = (((long)bk*NC + c)*DI + d)*NS + n0;
    *(float4*)(hloc + ho)     = make_float4(h[0],h[1],h[2],h[3]);
    *(float4*)(hloc + ho + 4) = make_float4(h[4],h[5],h[6],h[7]);
    if (j == 0) Ssum[((long)bk*NC + c)*DI + d] = S;
}

// ---- 5. scan pass B: sequential chunk combine; hinit written in-place into hloc ----
__global__ __launch_bounds__(256) void k_scanB(float* __restrict__ hloc, const float* __restrict__ Ssum,
                                               const float* __restrict__ alog){
    int gid = blockIdx.x * 256 + threadIdx.x;       // < BB*KK*DI*NS = 49152
    int dn = gid % (DI*NS);
    int bk = gid / (DI*NS);
    int d = dn >> 4, n = dn & 15;
    int k = bk & 3;
    float a = -__expf(alog[(k*DI + d)*NS + n]);
    float h = 0.f;
    long base  = (long)bk * NC * DI * NS + dn;
    long sbase = (long)bk * NC * DI + d;
#pragma unroll 4
    for (int c = 0; c < NC; ++c){
        long o = base + (long)c * DI * NS;
        float P = __expf(a * Ssum[sbase + (long)c * DI]);
        float tmp = hloc[o];
        hloc[o] = h;
        h = h * P + tmp;
    }
}

// ---- 6. scan pass C: replay with correct initial state, emit y at SPATIAL position ----
__global__ __launch_bounds__(192) void k_scanC(const float* __restrict__ delta, const float* __restrict__ bc2,
                                               const float* __restrict__ xc, const float* __restrict__ alog,
                                               const float* __restrict__ hloc, float* __restrict__ ys){
    int tid = threadIdx.x;
    int j = tid & 1, dl = tid >> 1;
    int bid = blockIdx.x;
    int dg = bid & 1; int c = (bid >> 1) & 63; int bk = bid >> 7;
    int b = bk >> 2, k = bk & 3;
    int d = dg*96 + dl;
    int n0 = j*8;
    float a[8]; bool fast = true;
#pragma unroll
    for (int n = 0; n < 8; ++n){
        a[n] = -__expf(alog[(k*DI + d)*NS + n0 + n]);
        fast = fast && (fabsf(a[n] + (float)(n0 + n + 1)) < 1e-4f*(float)(n0 + n + 1));
    }
    int t0 = c * CL;
    int p0, st;
    if (k == 0){ p0 = t0;         st = 1;   }
    else if (k == 1){ p0 = c;     st = 64;  }
    else if (k == 2){ p0 = LL-1-t0; st = -1;  }
    else            { p0 = LL-1-c;  st = -64; }
    const float* dep = delta + ((long)bk*LL + t0)*DI + d;
    const float* bcp = bc2   + ((long)bk*LL + t0)*32 + n0;
    const float* up  = xc + ((long)b*LL + p0)*DI + d;
    float*       yp  = ys + ((long)bk*LL + p0)*DI + d;
    long ustep = (long)st * DI;
    long ho = (((long)bk*NC + c)*DI + d)*NS + n0;
    float4 h03 = *(const float4*)(hloc + ho);
    float4 h47 = *(const float4*)(hloc + ho + 4);
    float h[8] = {h03.x,h03.y,h03.z,h03.w,h47.x,h47.y,h47.z,h47.w};
    if (fast){
        for (int i = 0; i < CL; ++i){
            float de = *dep;
            float u  = *up;
            float4 bv0 = *(const float4*)(bcp);
            float4 bv1 = *(const float4*)(bcp + 4);
            float4 cv0 = *(const float4*)(bcp + 16);
            float4 cv1 = *(const float4*)(bcp + 20);
            float E  = __expf(-de);
            float E2 = E*E, E4 = E2*E2, E8 = E4*E4;
            float e  = j ? E8 : 1.f;
            float du = de * u;
            float bb[8] = {bv0.x,bv0.y,bv0.z,bv0.w,bv1.x,bv1.y,bv1.z,bv1.w};
            float cc[8] = {cv0.x,cv0.y,cv0.z,cv0.w,cv1.x,cv1.y,cv1.z,cv1.w};
            float y = 0.f;
#pragma unroll
            for (int n = 0; n < 8; ++n){ e *= E; h[n] = h[n]*e + du*bb[n]; y += h[n]*cc[n]; }
            y += __shfl_xor(y, 1, 64);
            if (j == 0) *yp = y;
            dep += DI; up += ustep; yp += ustep; bcp += 32;
        }
    } else {
        for (int i = 0; i < CL; ++i){
            float de = *dep;
            float u  = *up;
            float4 bv0 = *(const float4*)(bcp);
            float4 bv1 = *(const float4*)(bcp + 4);
            float4 cv0 = *(const float4*)(bcp + 16);
            float4 cv1 = *(const float4*)(bcp + 20);
            float du = de * u;
            float bb[8] = {bv0.x,bv0.y,bv0.z,bv0.w,bv1.x,bv1.y,bv1.z,bv1.w};
            float cc[8] = {cv0.x,cv0.y,cv0.z,cv0.w,cv1.x,cv1.y,cv1.z,cv1.w};
            float y = 0.f;
#pragma unroll
            for (int n = 0; n < 8; ++n){ float dA = __expf(de*a[n]); h[n] = h[n]*dA + du*bb[n]; y += h[n]*cc[n]; }
            y += __shfl_xor(y, 1, 64);
            if (j == 0) *yp = y;
            dep += DI; up += ustep; yp += ustep; bcp += 32;
        }
    }
}

// ---- 7. merge(4 dirs) + D*u skip + LayerNorm + SiLU gate + out_proj -> fp32 out ----
__global__ __launch_bounds__(192) void k_fuse(const float* __restrict__ ys, const float* __restrict__ xc,
                                              const float* __restrict__ z, const float* __restrict__ Dsk,
                                              const float* __restrict__ lnw, const float* __restrict__ lnb,
                                              const float* __restrict__ wout, float* __restrict__ out){
    __shared__ float yv[4][DI];
    __shared__ float red[2][3];
    __shared__ float part[2][4][96];
    int tid = threadIdx.x;
    int b  = blockIdx.x / (LL/4);
    int p0 = (blockIdx.x % (LL/4)) * 4;
    int d = tid;
    float sumD = Dsk[d] + Dsk[DI + d] + Dsk[2*DI + d] + Dsk[3*DI + d];
    float lw = lnw[d], lb = lnb[d];
    for (int pp = 0; pp < 4; ++pp){
        int p = p0 + pp;
        long yb = ((long)b*4)*LL*DI + (long)p*DI + d;
        float y = ys[yb] + ys[yb + (long)LL*DI] + ys[yb + 2L*LL*DI] + ys[yb + 3L*LL*DI];
        y += xc[((long)b*LL + p)*DI + d] * sumD;
        float s = y, sq = y*y;
#pragma unroll
        for (int m = 32; m > 0; m >>= 1){ s += __shfl_down(s, m, 64); sq += __shfl_down(sq, m, 64); }
        int wvi = tid >> 6, ln = tid & 63;
        if (ln == 0){ red[0][wvi] = s; red[1][wvi] = sq; }
        __syncthreads();
        float st  = red[0][0] + red[0][1] + red[0][2];
        float sqt = red[1][0] + red[1][1] + red[1][2];
        float mu  = st / DI;
        float var = sqt / DI - mu*mu;
        float rs  = rsqrtf(var + 1e-5f);
        float yn  = (y - mu)*rs*lw + lb;
        float zg  = z[((long)b*LL + p)*DI + d];
        yv[pp][d] = yn * silu(zg);
        __syncthreads();
    }
    int m = tid % 96, half = tid / 96;
    float acc[4] = {0.f, 0.f, 0.f, 0.f};
    const float* wr = wout + (long)m*DI + half*96;
    for (int dd = 0; dd < 96; ++dd){
        float wv = wr[dd];
        int df = half*96 + dd;
#pragma unroll
        for (int pp = 0; pp < 4; ++pp) acc[pp] += wv * yv[pp][df];
    }
#pragma unroll
    for (int pp = 0; pp < 4; ++pp) part[half][pp][m] = acc[pp];
    __syncthreads();
    if (tid < 96){
#pragma unroll
        for (int pp = 0; pp < 4; ++pp){
            float v = part[0][pp][tid] + part[1][pp][tid];
            out[((long)b*LL + p0 + pp)*DM + tid] = v;
        }
    }
}

extern "C" void kernel_launch(void* const* d_in, const int* in_sizes, int n_in,
                              void* d_out, int out_size, void* d_ws, size_t ws_size,
                              hipStream_t stream){
    (void)in_sizes; (void)n_in; (void)out_size; (void)ws_size;
    const float* x    = (const float*)d_in[0];
    const float* win  = (const float*)d_in[1];
    const float* cw   = (const float*)d_in[2];
    const float* cb   = (const float*)d_in[3];
    const float* xpw  = (const float*)d_in[4];
    const float* dtw  = (const float*)d_in[5];
    const float* dtb  = (const float*)d_in[6];
    const float* alog = (const float*)d_in[7];
    const float* ds   = (const float*)d_in[8];
    const float* lnw  = (const float*)d_in[9];
    const float* lnb  = (const float*)d_in[10];
    const float* wout = (const float*)d_in[11];

    float* ws    = (float*)d_ws;
    float* xin   = ws + OFF_XIN;
    float* z     = ws + OFF_Z;
    float* xc    = ws + OFF_XC;
    float* delta = ws + OFF_DELTA;
    float* bc2   = ws + OFF_BC;
    float* ysb   = ws + OFF_YS;
    float* Ssum  = ws + OFF_S;
    float* hloc  = ws + OFF_HLOC;   // aliases xin (dead after k_conv)

    k_inproj<<<dim3(2048), dim3(384), 0, stream>>>(x, win, xin, z);
    k_conv  <<<dim3(12288), dim3(256), 0, stream>>>(xin, cw, cb, xc);
    k_xdbl  <<<dim3(2048), dim3(256), 0, stream>>>(xc, xpw, dtw, dtb, delta, bc2);
    k_scanA <<<dim3(2048), dim3(192), 0, stream>>>(delta, bc2, xc, alog, hloc, Ssum);
    k_scanB <<<dim3(192),  dim3(256), 0, stream>>>(hloc, Ssum, alog);
    k_scanC <<<dim3(2048), dim3(192), 0, stream>>>(delta, bc2, xc, alog, hloc, ysb);
    k_fuse  <<<dim3(4096), dim3(192), 0, stream>>>(ysb, xc, z, ds, lnw, lnb, wout,
                                                   (float*)d_out);
}